// Round 7
// baseline (78.177 us; speedup 1.0000x reference)
//
#include <hip/hip_runtime.h>

#define HIDDEN 128

typedef float v4f __attribute__((ext_vector_type(4)));

__device__ __forceinline__ float dot4(const v4f a, const v4f b) {
    return a.x * b.x + a.y * b.y + a.z * b.z + a.w * b.w;
}

// Pass 1 (single launch, two independent block roles — both pure HBM streams,
// so they overlap and keep HBM saturated end-to-end):
//   edge blocks [0, edge_blocks):   out[e] = dot(edge_hidden[e], W[0:128])
//   node blocks [edge_blocks, ...): nsd[n] = {dot(node[n],W_s), dot(node[n],W_d)}
__global__ __launch_bounds__(256)
void pass1_kernel(const float* __restrict__ node_hidden,
                  const float* __restrict__ edge_hidden,
                  const float* __restrict__ W,    // [384]
                  float2* __restrict__ nsd,       // [n_nodes]
                  float* __restrict__ out,        // [n_edges] (partial: dot only)
                  int n_nodes, int n_edges, int edge_blocks) {
    const int lane = threadIdx.x & 31;

    if ((int)blockIdx.x < edge_blocks) {
        // ---- edge-dot role: 4 edges per 32-lane group ----
        const int tid = blockIdx.x * blockDim.x + threadIdx.x;
        const int grp = tid >> 5;
        const int e0  = grp * 4;
        if (e0 >= n_edges) return;

        const v4f we = reinterpret_cast<const v4f*>(W)[lane];
        const v4f* r = reinterpret_cast<const v4f*>(edge_hidden) + (size_t)e0 * 32 + lane;
        const v4f x0 = r[0];
        const v4f x1 = r[32];
        const v4f x2 = r[64];
        const v4f x3 = r[96];

        float a0 = dot4(x0, we);
        float a1 = dot4(x1, we);
        float a2 = dot4(x2, we);
        float a3 = dot4(x3, we);

        #pragma unroll
        for (int off = 16; off > 0; off >>= 1) {
            a0 += __shfl_xor(a0, off, 32);
            a1 += __shfl_xor(a1, off, 32);
            a2 += __shfl_xor(a2, off, 32);
            a3 += __shfl_xor(a3, off, 32);
        }

        const int my_e = e0 + lane;
        if (lane < 4 && my_e < n_edges) {
            const float a = (lane == 0) ? a0 : (lane == 1) ? a1 : (lane == 2) ? a2 : a3;
            out[my_e] = a;
        }
    } else {
        // ---- node-dot role: 1 node per 32-lane group ----
        const int tid  = (blockIdx.x - edge_blocks) * blockDim.x + threadIdx.x;
        const int node = tid >> 5;
        if (node >= n_nodes) return;

        const v4f v  = reinterpret_cast<const v4f*>(node_hidden + (size_t)node * HIDDEN)[lane];
        const v4f ws = reinterpret_cast<const v4f*>(W + HIDDEN)[lane];
        const v4f wd = reinterpret_cast<const v4f*>(W + 2 * HIDDEN)[lane];

        float as = dot4(v, ws);
        float ad = dot4(v, wd);

        #pragma unroll
        for (int off = 16; off > 0; off >>= 1) {
            as += __shfl_down(as, off, 32);
            ad += __shfl_down(ad, off, 32);
        }
        if (lane == 0)
            nsd[node] = make_float2(as, ad);
    }
}

// Pass 2: out[e] += nsd[src].x + nsd[dst].y + b. One edge per lane; the 800 KB
// nsd table is L2/L3-resident; indices and out are coalesced streams.
__global__ __launch_bounds__(256)
void add_base_kernel(const int* __restrict__ edge_index, // [2][n_edges]
                     const float2* __restrict__ nsd,
                     const float* __restrict__ b,
                     float* __restrict__ out,
                     int n_edges) {
    const int e = blockIdx.x * blockDim.x + threadIdx.x;
    if (e >= n_edges) return;
    const int s = edge_index[e];
    const int d = edge_index[n_edges + e];
    out[e] += nsd[s].x + nsd[d].y + b[0];
}

extern "C" void kernel_launch(void* const* d_in, const int* in_sizes, int n_in,
                              void* d_out, int out_size, void* d_ws, size_t ws_size,
                              hipStream_t stream) {
    const float* node_hidden = (const float*)d_in[0];
    const float* edge_hidden = (const float*)d_in[1];
    const int*   edge_index  = (const int*)d_in[2];
    const float* W           = (const float*)d_in[3];
    const float* b           = (const float*)d_in[4];
    float* out = (float*)d_out;

    const int n_nodes = in_sizes[0] / HIDDEN;
    const int n_edges = in_sizes[2] / 2;

    float2* nsd = (float2*)d_ws;   // 800 KB

    {
        const int threads = 256;
        const int edge_groups = (n_edges + 3) / 4;                 // 4 edges / 32-lane group
        const int edge_blocks = (edge_groups * 32 + threads - 1) / threads;
        const int node_blocks = (n_nodes * 32 + threads - 1) / threads;
        pass1_kernel<<<edge_blocks + node_blocks, threads, 0, stream>>>(
            node_hidden, edge_hidden, W, nsd, out, n_nodes, n_edges, edge_blocks);
    }
    {
        const int threads = 256;
        const int blocks = (n_edges + threads - 1) / threads;
        add_base_kernel<<<blocks, threads, 0, stream>>>(edge_index, nsd, b, out, n_edges);
    }
}